// Round 5
// baseline (12748.756 us; speedup 1.0000x reference)
//
#include <hip/hip_runtime.h>
#include <hip/hip_bf16.h>

// Collapsed-projector persistent-GRU kernel for MI355X.
// Round 11: move the 64-party h-exchange from the MALL into a single XCD's L2.
// Evidence: R8/R9/R10 tried 3 protocols; traffic/VALU collapsed, time pinned
// at ~3.3ms -> the floor is MALL store->load visibility latency, serialized
// ~3-4x/step. Same-XCD blocks share a physical L2 (L1 is write-through; sc0
// ops bypass L1, hit L2) -> run the whole exchange at L2 latency.
//
// Structure: 8 groups x MB=8 batch rows; 256 blocks x 512 threads (each block
// merges two 16-col slices, 8 waves); group g = bid&7 (round-robin XCD hint),
// 32 blocks/group = one XCD at 1 block/CU (residency guaranteed).
// Safety (mapping is officially undefined):
//  - init PROBE: each block sc0-stores a marker; all poll all 32 via sc0;
//    passes only on a truly shared L2. Group-wide VOTE via MALL -> agreed
//    fast/fallback (no mixed scopes possible).
//  - per-step DEGRADE VALVE: stall > ~16k polls -> republish via MALL, flip
//    group to MALL forever (wrong assumptions => one-time ms cost, not hang).
//  - fast and MALL paths use DISJOINT buffers; fast flags carry a persistent
//    EPOCH (non-memset counter) so stale L2 lines across graph replays can
//    never satisfy a new launch's rendezvous.

#define HIDDEN 1024
#define INDIM  63
#define TSEQ   512
#define MB     8
#define GROUPS 8
#define PAYDW  4096      // dwords per (parity, group) payload = 16 KB

typedef __attribute__((ext_vector_type(8))) short bfrag8;  // 8 bf16 in 4 VGPRs
typedef __attribute__((ext_vector_type(4))) float ffrag4;  // MFMA accumulator
typedef __attribute__((ext_vector_type(4))) unsigned u32x4;
typedef __attribute__((ext_vector_type(2))) unsigned u32x2;
typedef unsigned long long ull;

#define MFMA_B16(a, b, c) __builtin_amdgcn_mfma_f32_16x16x32_bf16((a), (b), (c), 0, 0, 0)

__device__ __forceinline__ short f2bf(float x) {
  __hip_bfloat16 b = __float2bfloat16(x);
  return __builtin_bit_cast(short, b);
}
__device__ __forceinline__ float bf2f(short s) {
  unsigned u = ((unsigned)(unsigned short)s) << 16;
  return __builtin_bit_cast(float, u);
}

// ---------------- precompute kernels ----------------

__global__ void k_t1(const float* __restrict__ W2, const float* __restrict__ b1,
                     const float* __restrict__ b2, float* __restrict__ t1) {
  const int w = threadIdx.x >> 6, lane = threadIdx.x & 63;
  const int o = blockIdx.x * 4 + w;
  if (o >= HIDDEN) return;
  const float* row = W2 + (size_t)o * HIDDEN;
  float s = 0.f;
  for (int k = lane; k < HIDDEN; k += 64) s += row[k] * b1[k];
  for (int off = 32; off; off >>= 1) s += __shfl_down(s, off, 64);
  if (lane == 0) t1[o] = s + b2[o];
}

__global__ void k_bp(const float* __restrict__ W3, const float* __restrict__ t1,
                     const float* __restrict__ b3, float* __restrict__ bp) {
  const int w = threadIdx.x >> 6, lane = threadIdx.x & 63;
  for (int d = w; d < INDIM; d += 4) {
    const float* row = W3 + (size_t)d * HIDDEN;
    float s = 0.f;
    for (int k = lane; k < HIDDEN; k += 64) s += row[k] * t1[k];
    for (int off = 32; off; off >>= 1) s += __shfl_down(s, off, 64);
    if (lane == 0) bp[d] = s + b3[d];
  }
}

__global__ void k_gemm(const float* __restrict__ A, const float* __restrict__ B,
                       float* __restrict__ C, int M, int N, int K) {
  __shared__ float As[16][17], Bs[16][17];
  const int tx = threadIdx.x, ty = threadIdx.y;
  const int row = blockIdx.y * 16 + ty;
  const int col = blockIdx.x * 16 + tx;
  float acc = 0.f;
  for (int k0 = 0; k0 < K; k0 += 16) {
    As[ty][tx] = (row < M) ? A[(size_t)row * K + k0 + tx] : 0.f;
    Bs[ty][tx] = B[(size_t)(k0 + ty) * N + col];
    __syncthreads();
#pragma unroll
    for (int kk = 0; kk < 16; ++kk) acc += As[ty][kk] * Bs[kk][tx];
    __syncthreads();
  }
  if (row < M && col < N) C[(size_t)row * N + col] = acc;
}

// ---------------- main persistent kernel ----------------

__global__ __launch_bounds__(512, 2) void k_main(
    const float* __restrict__ X,
    const float* __restrict__ W_ih, const float* __restrict__ W_hh,
    const float* __restrict__ b_ih, const float* __restrict__ b_hh,
    const float* __restrict__ WpF, const float* __restrict__ bpF,
    const int* __restrict__ pCL, const int* __restrict__ pGT,
    unsigned* __restrict__ ctrl, unsigned* __restrict__ hbM,
    unsigned* __restrict__ hbF, float* __restrict__ OUT) {
  __shared__ short h_st[16][HIDDEN + 8];   // rows 8..15 stay zero (MB=8)
  __shared__ short inp_bf[16][88];
  __shared__ float inp_f[16][68];
  __shared__ float gt_z[2][16][20], gt_hn[2][16][20];
  __shared__ float gt_ir[2][16][20], gt_iz[2][16][20], gt_in[2][16][20];
  __shared__ short htmp[2][16][20];

  const int tid = threadIdx.x;
  const int w8 = tid >> 6;         // wave 0..7
  const int lane = tid & 63;
  const int sl = w8 >> 2;          // slice 0/1
  const int ww = w8 & 3;           // role within slice
  const int c = lane & 15;
  const int quad = lane >> 4;
  const int bid = blockIdx.x;
  const int g = bid & 7;           // group == XCD hint (round-robin)
  const int blockj = bid >> 3;     // 0..31
  const int js = blockj * 2 + sl;  // col-slice 0..63

  // ---- ctrl carve-up (dwords). [memset 0..2400) each launch; epoch NOT] ----
  unsigned* flM = ctrl;                  // [8][64] u32  MALL flags
  unsigned* xa  = ctrl + 512;            // [8][32] init barrier
  unsigned* vt  = ctrl + 768;            // [8][32] votes
  unsigned* dg  = ctrl + 1024;           // [8] degrade
  unsigned* pw  = ctrl + 1056;           // [8][32] probe markers
  ull* ebc      = (ull*)(ctrl + 1344);   // epoch broadcast
  ull* flF      = (ull*)(ctrl + 1376);   // [8][64] ull fast epoch-flags
  ull* epoch    = (ull*)(ctrl + 2400);   // persistent, NOT memset

  unsigned* flMg = flM + g * 64;
  ull*      flFg = flF + g * 64;
  unsigned* dgg  = dg + g;

  // ---- early: probe store + barrier mark + epoch fetch (bid 0) ----
  if (tid == 0) {
    unsigned* pp = pw + g * 32 + blockj;
    unsigned mk = 0xA5u;
    asm volatile("global_store_dword %0, %1, off sc0" :: "v"(pp), "v"(mk) : "memory");
    asm volatile("s_waitcnt vmcnt(0)" ::: "memory");
    __hip_atomic_store(xa + g * 32 + blockj, 1u, __ATOMIC_RELAXED,
                       __HIP_MEMORY_SCOPE_SYSTEM);
    if (bid == 0) {
      ull e = __hip_atomic_fetch_add(epoch, 1ull, __ATOMIC_RELAXED,
                                     __HIP_MEMORY_SCOPE_SYSTEM);
      __hip_atomic_store(ebc, (e << 1) | 1ull, __ATOMIC_RELAXED,
                         __HIP_MEMORY_SCOPE_SYSTEM);
    }
  }

  const int gtv = pGT[0];
  int period = pCL[0] + gtv;
  if (period < 1) period = 1;

  // ---- persistent register-resident weights (per slice) ----
  bfrag8 wB[32];
  if (ww < 3) {
    const float* wr = W_hh + ((size_t)ww * HIDDEN + (size_t)js * 16 + c) * HIDDEN;
#pragma unroll
    for (int ks = 0; ks < 32; ++ks) {
      const float* p = wr + ks * 32 + quad * 8;
      bfrag8 f;
#pragma unroll
      for (int e = 0; e < 8; ++e) f[e] = f2bf(p[e]);
      wB[ks] = f;
    }
  } else {
#pragma unroll
    for (int gate = 0; gate < 3; ++gate) {
      const float* wr = W_ih + ((size_t)gate * HIDDEN + (size_t)js * 16 + c) * INDIM;
#pragma unroll
      for (int ks = 0; ks < 2; ++ks) {
        bfrag8 f;
#pragma unroll
        for (int e = 0; e < 8; ++e) {
          int k = ks * 32 + quad * 8 + e;
          f[e] = (k < INDIM) ? f2bf(wr[k]) : (short)0;
        }
        wB[gate * 2 + ks] = f;
      }
    }
  }
  const int dd = 16 * w8 + c;      // projector dim (waves 0-3 only)
  bfrag8 wp[32];
  if (w8 < 4) {
    const float* wr = WpF + (size_t)dd * HIDDEN;
#pragma unroll
    for (int ks = 0; ks < 32; ++ks) {
      bfrag8 f;
#pragma unroll
      for (int e = 0; e < 8; ++e)
        f[e] = (dd < INDIM) ? f2bf(wr[ks * 32 + quad * 8 + e]) : (short)0;
      wp[ks] = f;
    }
  }

  float bias_g;
  if (ww == 0)      bias_g = b_ih[js * 16 + c] + b_hh[js * 16 + c];
  else if (ww == 1) bias_g = b_ih[HIDDEN + js * 16 + c] + b_hh[HIDDEN + js * 16 + c];
  else if (ww == 2) bias_g = b_hh[2 * HIDDEN + js * 16 + c];
  else              bias_g = b_ih[2 * HIDDEN + js * 16 + c];
  const float bp_l = (w8 < 4 && dd < INDIM) ? bpF[dd] : 0.f;

  for (int i = tid; i < 16 * (HIDDEN + 8); i += 512) ((short*)h_st)[i] = 0;
  for (int i = tid; i < 16 * 88; i += 512) ((short*)inp_bf)[i] = 0;
  for (int i = tid; i < 16 * 68; i += 512) ((float*)inp_f)[i] = 0.f;

  // ---- init rendezvous (doubles as start line; after weight loads) ----
  {  // group barrier: all 32 marks
    const unsigned* a = xa + g * 32 + (lane & 31);
    while (__hip_atomic_load(a, __ATOMIC_RELAXED, __HIP_MEMORY_SCOPE_SYSTEM) == 0)
      __builtin_amdgcn_s_sleep(2);
  }
  if (tid < 64) {  // wave 0: bounded probe of all 32 markers via sc0 (L2)
    const unsigned* pp = pw + g * 32 + (lane & 31);
    int okp = 0;
    for (int it = 0; it < 64; ++it) {
      unsigned v;
      asm volatile("global_load_dword %0, %1, off sc0" : "=v"(v) : "v"(pp) : "memory");
      asm volatile("s_waitcnt vmcnt(0)" ::: "memory");
      __builtin_amdgcn_sched_barrier(0);
      if (__ballot(v == 0) == 0ull) { okp = 1; break; }
      __builtin_amdgcn_s_sleep(2);
    }
    if (lane == 0)
      __hip_atomic_store(vt + g * 32 + blockj, okp ? 1u : 2u,
                         __ATOMIC_RELAXED, __HIP_MEMORY_SCOPE_SYSTEM);
  }
  bool fast;
  {  // all waves: agree on the group decision via MALL votes
    const unsigned* vv = vt + g * 32 + (lane & 31);
    unsigned mv;
    while ((mv = __hip_atomic_load(vv, __ATOMIC_RELAXED,
                                   __HIP_MEMORY_SCOPE_SYSTEM)) == 0)
      __builtin_amdgcn_s_sleep(2);
    fast = (__ballot(mv != 1u) == 0ull);
  }
  ull ftg_base;
  {  // epoch broadcast
    ull e;
    while (((e = __hip_atomic_load(ebc, __ATOMIC_RELAXED,
                                   __HIP_MEMORY_SCOPE_SYSTEM)) & 1ull) == 0)
      __builtin_amdgcn_s_sleep(2);
    ftg_base = (e >> 1) << 10;  // epoch*1024; monotone across graph replays
  }

  unsigned* hbMg[2] = {hbM + g * PAYDW, hbM + (8 + g) * PAYDW};
  unsigned* hbFg[2] = {hbF + g * PAYDW, hbF + (8 + g) * PAYDW};

  // X prefetch registers (teacher-forcing rows; threads 0..127 cover 8x16)
  const int xrow = tid >> 4, xd0 = (tid & 15) * 4;
  float xp[4];
  if (tid < 128 && 0 < gtv) {
    const float* xr = X + ((size_t)(g * MB + xrow) * TSEQ + 0) * INDIM;
#pragma unroll
    for (int e = 0; e < 4; ++e) xp[e] = (xd0 + e < INDIM) ? xr[xd0 + e] : 0.f;
  }

  for (int t = 0; t < TSEQ; ++t) {
    const unsigned tg = (unsigned)(t + 1);
    const ull ftg = ftg_base + (ull)tg;
    const bool teach = ((t % period) < gtv);
    if (teach && tid < 128) {
#pragma unroll
      for (int e = 0; e < 4; ++e) {
        inp_f[xrow][xd0 + e] = xp[e];
        inp_bf[xrow][xd0 + e] = f2bf(xp[e]);
      }
    }
    __syncthreads();  // S1: inp ready; h_st holds h(t-1)

    ffrag4 ghr;
    float hp[4];
    if (ww < 3) {
      ffrag4 acc[4];
#pragma unroll
      for (int e = 0; e < 4; ++e) {
        acc[0][e] = bias_g; acc[1][e] = 0.f; acc[2][e] = 0.f; acc[3][e] = 0.f;
      }
#pragma unroll
      for (int ks = 0; ks < 32; ++ks) {
        const bfrag8 a = *(const bfrag8*)&h_st[c][ks * 32 + quad * 8];
        acc[ks & 3] = MFMA_B16(a, wB[ks], acc[ks & 3]);
      }
      ffrag4 gsum = acc[0] + acc[1] + acc[2] + acc[3];
      if (ww == 1) {
#pragma unroll
        for (int i = 0; i < 4; ++i) gt_z[sl][quad * 4 + i][c] = gsum[i];
      } else if (ww == 2) {
#pragma unroll
        for (int i = 0; i < 4; ++i) gt_hn[sl][quad * 4 + i][c] = gsum[i];
      } else {
        ghr = gsum;
#pragma unroll
        for (int i = 0; i < 4; ++i) hp[i] = bf2f(h_st[quad * 4 + i][js * 16 + c]);
      }
    } else {
      ffrag4 gir, giz, gin;
#pragma unroll
      for (int e = 0; e < 4; ++e) { gir[e] = 0.f; giz[e] = 0.f; gin[e] = bias_g; }
#pragma unroll
      for (int ks = 0; ks < 2; ++ks) {
        const bfrag8 a = *(const bfrag8*)&inp_bf[c][ks * 32 + quad * 8];
        gir = MFMA_B16(a, wB[0 + ks], gir);
        giz = MFMA_B16(a, wB[2 + ks], giz);
        gin = MFMA_B16(a, wB[4 + ks], gin);
      }
#pragma unroll
      for (int i = 0; i < 4; ++i) {
        gt_ir[sl][quad * 4 + i][c] = gir[i];
        gt_iz[sl][quad * 4 + i][c] = giz[i];
        gt_in[sl][quad * 4 + i][c] = gin[i];
      }
    }
    __syncthreads();  // S2: gate tiles ready

    unsigned* hwF = hbFg[t & 1];
    unsigned* hwM = hbMg[t & 1];
    unsigned pv = 0;
    unsigned* pdM = hwM;  // init to silence; real value set for ww==0
    if (ww == 0) {
      // gates -> h_new (rows 0..7 real) -> packed publish
#pragma unroll
      for (int i = 0; i < 4; ++i) {
        const int row = quad * 4 + i;
        float r = 1.f / (1.f + __expf(-(ghr[i] + gt_ir[sl][row][c])));
        float z = 1.f / (1.f + __expf(-(gt_z[sl][row][c] + gt_iz[sl][row][c])));
        float n = tanhf(gt_in[sl][row][c] + r * gt_hn[sl][row][c]);
        htmp[sl][row][c] = f2bf((1.f - z) * n + z * hp[i]);
      }
      asm volatile("" ::: "memory");
      const int r = lane >> 3, cp = lane & 7;  // 8 rows x 8 dword-cols
      pv = (unsigned)(unsigned short)htmp[sl][r][cp * 2] |
           ((unsigned)(unsigned short)htmp[sl][r][cp * 2 + 1] << 16);
      unsigned* pdF = hwF + r * 512 + js * 8 + cp;
      pdM = hwM + r * 512 + js * 8 + cp;
      if (fast) {
        asm volatile("global_store_dword %0, %1, off sc0" :: "v"(pdF), "v"(pv) : "memory");
        asm volatile("s_waitcnt vmcnt(0)" ::: "memory");  // drained to shared L2
        if (lane == 0) {
          u32x2 fw; fw[0] = (unsigned)ftg; fw[1] = (unsigned)(ftg >> 32);
          ull* fdst = flFg + js;
          asm volatile("global_store_dwordx2 %0, %1, off sc0" :: "v"(fdst), "v"(fw) : "memory");
        }
      } else {
        asm volatile("global_store_dword %0, %1, off sc0 sc1" :: "v"(pdM), "v"(pv) : "memory");
        asm volatile("s_waitcnt vmcnt(0)" ::: "memory");  // drained to MALL
        if (lane == 0)
          __hip_atomic_store(&flMg[js], tg, __ATOMIC_RELAXED,
                             __HIP_MEMORY_SCOPE_SYSTEM);
      }
    }

    // X(t+1) loads fly during the rendezvous
    if (tid < 128) {
      const int tn = t + 1;
      if (tn < TSEQ && ((tn % period) < gtv)) {
        const float* xr = X + ((size_t)(g * MB + xrow) * TSEQ + tn) * INDIM;
#pragma unroll
        for (int e = 0; e < 4; ++e) xp[e] = (xd0 + e < INDIM) ? xr[xd0 + e] : 0.f;
      }
    }

    // rendezvous: all 64 slice-flags >= target
    if (fast) {
      const ull* fa = flFg + lane;  // one 8B epoch-flag per lane
      int it = 0;
      for (;;) {
        u32x2 fw;
        asm volatile("global_load_dwordx2 %0, %1, off sc0" : "=v"(fw) : "v"(fa) : "memory");
        asm volatile("s_waitcnt vmcnt(0)" ::: "memory");
        __builtin_amdgcn_sched_barrier(0);
        ull fv = ((ull)fw[1] << 32) | (ull)fw[0];
        if (__ballot(fv < ftg) == 0ull) break;
        __builtin_amdgcn_s_sleep(1);
        if (((++it) & 255) == 0) {  // degrade valve (perf-safety, not correctness)
          unsigned dv = __hip_atomic_load(dgg, __ATOMIC_RELAXED,
                                          __HIP_MEMORY_SCOPE_SYSTEM);
          if (dv || it > 16384) {
            __hip_atomic_store(dgg, 1u, __ATOMIC_RELAXED, __HIP_MEMORY_SCOPE_SYSTEM);
            fast = false;
            if (ww == 0) {  // republish current step via MALL
              asm volatile("global_store_dword %0, %1, off sc0 sc1" :: "v"(pdM), "v"(pv) : "memory");
              asm volatile("s_waitcnt vmcnt(0)" ::: "memory");
              if (lane == 0)
                __hip_atomic_store(&flMg[js], tg, __ATOMIC_RELAXED,
                                   __HIP_MEMORY_SCOPE_SYSTEM);
            }
            break;
          }
        }
      }
    }
    if (!fast) {
      const unsigned* fa = flMg + (lane & 15) * 4;
      for (;;) {
        u32x4 fv;
        asm volatile("global_load_dwordx4 %0, %1, off sc0 sc1" : "=v"(fv) : "v"(fa) : "memory");
        asm volatile("s_waitcnt vmcnt(0)" ::: "memory");
        __builtin_amdgcn_sched_barrier(0);
        bool ok = fv[0] >= tg && fv[1] >= tg && fv[2] >= tg && fv[3] >= tg;
        if (__ballot(!ok) == 0ull) break;
        __builtin_amdgcn_s_sleep(1);
      }
    }

    // gather h(t): 32B/thread, single round (flag-gated; no tags needed)
    {
      const unsigned* gp = (fast ? hwF : hwM) + (size_t)tid * 4;
      u32x4 v0, v1;
      if (fast) {
        asm volatile("global_load_dwordx4 %0, %1, off sc0" : "=v"(v0) : "v"(gp) : "memory");
        asm volatile("global_load_dwordx4 %0, %1, off sc0" : "=v"(v1) : "v"(gp + 2048) : "memory");
      } else {
        asm volatile("global_load_dwordx4 %0, %1, off sc0 sc1" : "=v"(v0) : "v"(gp) : "memory");
        asm volatile("global_load_dwordx4 %0, %1, off sc0 sc1" : "=v"(v1) : "v"(gp + 2048) : "memory");
      }
      asm volatile("s_waitcnt vmcnt(0)" ::: "memory");
      __builtin_amdgcn_sched_barrier(0);
      *(u32x4*)&h_st[tid >> 7][(tid & 127) * 8] = v0;
      const int u1 = tid + 512;
      *(u32x4*)&h_st[u1 >> 7][(u1 & 127) * 8] = v1;
    }
    __syncthreads();  // S3: h_st = h(t)

    // out(t) = inp(t) + h(t) @ Wp^T + bp   (waves 0-3; rows 0..7 real)
    const int wj = t & 31;
    const bool rep = (t + 1 < TSEQ) && !(((t + 1) % period) < gtv);
    if (w8 < 4 && (rep || blockj == wj)) {
      ffrag4 oa0, oa1;
#pragma unroll
      for (int e = 0; e < 4; ++e) { oa0[e] = bp_l; oa1[e] = 0.f; }
#pragma unroll
      for (int ks = 0; ks < 32; ++ks) {
        const bfrag8 a = *(const bfrag8*)&h_st[c][ks * 32 + quad * 8];
        if (ks & 1) oa1 = MFMA_B16(a, wp[ks], oa1);
        else        oa0 = MFMA_B16(a, wp[ks], oa0);
      }
      ffrag4 o = oa0 + oa1;
#pragma unroll
      for (int i = 0; i < 4; ++i) {
        const int row = quad * 4 + i;
        if (dd < INDIM) {
          float val = o[i] + inp_f[row][dd];
          if (blockj == wj && row < MB)
            OUT[((size_t)(g * MB + row) * TSEQ + t) * INDIM + dd] = val;
          if (rep) { inp_f[row][dd] = val; inp_bf[row][dd] = f2bf(val); }
        } else if (rep) {
          inp_bf[row][dd] = 0;
        }
      }
    }
    // loop-head S1 orders inp writes vs next gi reads
  }
}

// ---------------- host ----------------

extern "C" void kernel_launch(void* const* d_in, const int* in_sizes, int n_in,
                              void* d_out, int out_size, void* d_ws, size_t ws_size,
                              hipStream_t stream) {
  const float* X    = (const float*)d_in[0];
  const float* W_ih = (const float*)d_in[1];
  const float* W_hh = (const float*)d_in[2];
  const float* b_ih = (const float*)d_in[3];
  const float* b_hh = (const float*)d_in[4];
  const float* W1   = (const float*)d_in[5];
  const float* b1   = (const float*)d_in[6];
  const float* W2   = (const float*)d_in[7];
  const float* b2   = (const float*)d_in[8];
  const float* W3   = (const float*)d_in[9];
  const float* b3   = (const float*)d_in[10];
  const int* pCL    = (const int*)d_in[11];
  const int* pGT    = (const int*)d_in[12];
  float* OUT = (float*)d_out;

  // layout (bytes):
  //   1024: bp | 2048: t1 | 8192: Wp(258048)
  //   270336: T2 scratch (dead before k_main) aliases hbM [2][8][4096]u32 (256KB)
  //   532480: ctrl (9608B; dwords 0..2400 memset; epoch at dword 2400 NOT memset)
  //   544768: hbF [2][8][4096]u32 (256KB, fast/L2 region, never memset)
  char* ws = (char*)d_ws;
  float* bp = (float*)(ws + 1024);
  float* t1 = (float*)(ws + 2048);
  float* Wp = (float*)(ws + 8192);
  float* T2 = (float*)(ws + 270336);
  unsigned* hbM  = (unsigned*)(ws + 270336);
  unsigned* ctrl = (unsigned*)(ws + 532480);
  unsigned* hbF  = (unsigned*)(ws + 544768);
  if (ws_size < 795 * 1024) return;

  k_t1<<<256, 256, 0, stream>>>(W2, b1, b2, t1);
  k_gemm<<<dim3(64, 4), dim3(16, 16), 0, stream>>>(W3, W2, T2, INDIM, HIDDEN, HIDDEN);
  k_gemm<<<dim3(64, 4), dim3(16, 16), 0, stream>>>(T2, W1, Wp, INDIM, HIDDEN, HIDDEN);
  k_bp<<<1, 256, 0, stream>>>(W3, t1, b3, bp);
  hipMemsetAsync(ctrl, 0, 9600, stream);  // flags/barrier/votes/degrade/probe := 0
  k_main<<<256, 512, 0, stream>>>(X, W_ih, W_hh, b_ih, b_hh, Wp, bp, pCL, pGT,
                                  ctrl, hbM, hbF, OUT);
}

// Round 6
// 6044.454 us; speedup vs baseline: 2.1092x; 2.1092x over previous
//
#include <hip/hip_runtime.h>
#include <hip/hip_bf16.h>

// Collapsed-projector persistent-GRU kernel for MI355X.
// Round 12: XCD-local (shared-L2) h-exchange, register-safe geometry.
// R11's failure was VGPR starvation (launch_bounds(512,2) -> 128 regs -> full
// spill, FETCH 6.3GB), NOT the exchange idea. This round:
//  - 256-thread blocks, __launch_bounds__(256,1) -> 512-reg budget (R6-proven).
//  - Each block owns TWO 16-col slices: wB0[32]+wB1[32]+wp[32] ~ 450 regs peak.
//  - MB=8 rows x 8 groups; group = 32 blocks = one XCD (bid&7 round-robin).
//  - Exchange: 8B units (payload32 | epoch-tag32), self-validating, sc0-only
//    (stays in the XCD's L2). No flags, no drains: optimistic gather + retry.
//  - Safety: init probe+vote (behavioral shared-L2 test); per-step degrade
//    valve -> republish via MALL, retries alternate sc0/sc1 (no deadlock);
//    persistent epoch makes stale lines from any prior launch non-validating.

#define HIDDEN 1024
#define INDIM  63
#define TSEQ   512
#define MB     8
#define GROUPS 8
#define HBU    4096   // 8B units per (parity,group): 8 rows x 512 col-pairs

typedef __attribute__((ext_vector_type(8))) short bfrag8;  // 8 bf16 in 4 VGPRs
typedef __attribute__((ext_vector_type(4))) float ffrag4;  // MFMA accumulator
typedef __attribute__((ext_vector_type(4))) unsigned u32x4;
typedef __attribute__((ext_vector_type(2))) unsigned u32x2;
typedef unsigned long long ull;

#define MFMA_B16(a, b, c) __builtin_amdgcn_mfma_f32_16x16x32_bf16((a), (b), (c), 0, 0, 0)

__device__ __forceinline__ short f2bf(float x) {
  __hip_bfloat16 b = __float2bfloat16(x);
  return __builtin_bit_cast(short, b);
}
__device__ __forceinline__ float bf2f(short s) {
  unsigned u = ((unsigned)(unsigned short)s) << 16;
  return __builtin_bit_cast(float, u);
}

// ---------------- precompute kernels ----------------

__global__ void k_t1(const float* __restrict__ W2, const float* __restrict__ b1,
                     const float* __restrict__ b2, float* __restrict__ t1) {
  const int w = threadIdx.x >> 6, lane = threadIdx.x & 63;
  const int o = blockIdx.x * 4 + w;
  if (o >= HIDDEN) return;
  const float* row = W2 + (size_t)o * HIDDEN;
  float s = 0.f;
  for (int k = lane; k < HIDDEN; k += 64) s += row[k] * b1[k];
  for (int off = 32; off; off >>= 1) s += __shfl_down(s, off, 64);
  if (lane == 0) t1[o] = s + b2[o];
}

__global__ void k_bp(const float* __restrict__ W3, const float* __restrict__ t1,
                     const float* __restrict__ b3, float* __restrict__ bp) {
  const int w = threadIdx.x >> 6, lane = threadIdx.x & 63;
  for (int d = w; d < INDIM; d += 4) {
    const float* row = W3 + (size_t)d * HIDDEN;
    float s = 0.f;
    for (int k = lane; k < HIDDEN; k += 64) s += row[k] * t1[k];
    for (int off = 32; off; off >>= 1) s += __shfl_down(s, off, 64);
    if (lane == 0) bp[d] = s + b3[d];
  }
}

__global__ void k_gemm(const float* __restrict__ A, const float* __restrict__ B,
                       float* __restrict__ C, int M, int N, int K) {
  __shared__ float As[16][17], Bs[16][17];
  const int tx = threadIdx.x, ty = threadIdx.y;
  const int row = blockIdx.y * 16 + ty;
  const int col = blockIdx.x * 16 + tx;
  float acc = 0.f;
  for (int k0 = 0; k0 < K; k0 += 16) {
    As[ty][tx] = (row < M) ? A[(size_t)row * K + k0 + tx] : 0.f;
    Bs[ty][tx] = B[(size_t)(k0 + ty) * N + col];
    __syncthreads();
#pragma unroll
    for (int kk = 0; kk < 16; ++kk) acc += As[ty][kk] * Bs[kk][tx];
    __syncthreads();
  }
  if (row < M && col < N) C[(size_t)row * N + col] = acc;
}

// ---------------- main persistent kernel ----------------

__global__ __launch_bounds__(256, 1) void k_main(
    const float* __restrict__ X,
    const float* __restrict__ W_ih, const float* __restrict__ W_hh,
    const float* __restrict__ b_ih, const float* __restrict__ b_hh,
    const float* __restrict__ WpF, const float* __restrict__ bpF,
    const int* __restrict__ pCL, const int* __restrict__ pGT,
    unsigned* __restrict__ ctrl, ull* __restrict__ hb,
    float* __restrict__ OUT) {
  __shared__ short h_st[16][HIDDEN + 8];   // rows 8..15 stay zero (MB=8)
  __shared__ short inp_bf[16][88];
  __shared__ float inp_f[16][68];
  __shared__ float gt_z[2][16][20], gt_hn[2][16][20];
  __shared__ float gt_ir[2][16][20], gt_iz[2][16][20], gt_in[2][16][20];
  __shared__ short htmp[2][16][20];

  const int tid = threadIdx.x;
  const int w = tid >> 6, lane = tid & 63;
  const int c = lane & 15, quad = lane >> 4;
  const int bid = blockIdx.x;
  const int g = bid & 7;           // group == XCD hint (round-robin)
  const int blockj = bid >> 3;     // 0..31
  const int j0 = blockj * 2, j1 = j0 + 1;

  // ctrl carve (dword offsets; bytes [0,4080) memset each launch; epoch NOT)
  unsigned* pw = ctrl;                 // [8][32] probe markers
  unsigned* xa = ctrl + 256;           // [8][32] init barrier
  unsigned* vt = ctrl + 512;           // [8][32] votes
  unsigned* dg = ctrl + 768;           // [8] degrade
  ull* ebc     = (ull*)(ctrl + 776);   // epoch broadcast
  ull* epoch   = (ull*)(ctrl + 1020);  // persistent counter (byte 4080)

  // early: probe marker (L2) + barrier mark (MALL) + epoch fetch (bid 0)
  if (tid == 0) {
    unsigned* pp = pw + g * 32 + blockj;
    unsigned mk = 0xA5u;
    asm volatile("global_store_dword %0, %1, off sc0" :: "v"(pp), "v"(mk) : "memory");
    asm volatile("s_waitcnt vmcnt(0)" ::: "memory");
    __hip_atomic_store(xa + g * 32 + blockj, 1u, __ATOMIC_RELAXED,
                       __HIP_MEMORY_SCOPE_SYSTEM);
    if (bid == 0) {
      ull e = __hip_atomic_fetch_add(epoch, 1ull, __ATOMIC_RELAXED,
                                     __HIP_MEMORY_SCOPE_SYSTEM);
      __hip_atomic_store(ebc, (e << 1) | 1ull, __ATOMIC_RELAXED,
                         __HIP_MEMORY_SCOPE_SYSTEM);
    }
  }

  const int gtv = pGT[0];
  int period = pCL[0] + gtv;
  if (period < 1) period = 1;

  // --- persistent register-resident weights: TWO col-slices per block ---
  bfrag8 wB0[32], wB1[32], wp[32];
  if (w < 3) {
    const float* wr0 = W_hh + ((size_t)w * HIDDEN + (size_t)j0 * 16 + c) * HIDDEN;
    const float* wr1 = W_hh + ((size_t)w * HIDDEN + (size_t)j1 * 16 + c) * HIDDEN;
#pragma unroll
    for (int ks = 0; ks < 32; ++ks) {
      bfrag8 f0, f1;
#pragma unroll
      for (int e = 0; e < 8; ++e) {
        f0[e] = f2bf(wr0[ks * 32 + quad * 8 + e]);
        f1[e] = f2bf(wr1[ks * 32 + quad * 8 + e]);
      }
      wB0[ks] = f0; wB1[ks] = f1;
    }
  } else {
#pragma unroll
    for (int gate = 0; gate < 3; ++gate) {
      const float* wr0 = W_ih + ((size_t)gate * HIDDEN + (size_t)j0 * 16 + c) * INDIM;
      const float* wr1 = W_ih + ((size_t)gate * HIDDEN + (size_t)j1 * 16 + c) * INDIM;
#pragma unroll
      for (int ks = 0; ks < 2; ++ks) {
        bfrag8 f0, f1;
#pragma unroll
        for (int e = 0; e < 8; ++e) {
          int k = ks * 32 + quad * 8 + e;
          f0[e] = (k < INDIM) ? f2bf(wr0[k]) : (short)0;
          f1[e] = (k < INDIM) ? f2bf(wr1[k]) : (short)0;
        }
        wB0[gate * 2 + ks] = f0; wB1[gate * 2 + ks] = f1;
      }
    }
  }
  const int dd = 16 * w + c;
  {
    const float* wr = WpF + (size_t)dd * HIDDEN;
#pragma unroll
    for (int ks = 0; ks < 32; ++ks) {
      bfrag8 f;
#pragma unroll
      for (int e = 0; e < 8; ++e)
        f[e] = (dd < INDIM) ? f2bf(wr[ks * 32 + quad * 8 + e]) : (short)0;
      wp[ks] = f;
    }
  }

  float bias0, bias1;
  if (w == 0)      { bias0 = b_ih[j0*16+c] + b_hh[j0*16+c];
                     bias1 = b_ih[j1*16+c] + b_hh[j1*16+c]; }
  else if (w == 1) { bias0 = b_ih[HIDDEN + j0*16+c] + b_hh[HIDDEN + j0*16+c];
                     bias1 = b_ih[HIDDEN + j1*16+c] + b_hh[HIDDEN + j1*16+c]; }
  else if (w == 2) { bias0 = b_hh[2*HIDDEN + j0*16+c];
                     bias1 = b_hh[2*HIDDEN + j1*16+c]; }
  else             { bias0 = b_ih[2*HIDDEN + j0*16+c];
                     bias1 = b_ih[2*HIDDEN + j1*16+c]; }
  const float bp_l = (dd < INDIM) ? bpF[dd] : 0.f;

  for (int i = tid; i < 16 * (HIDDEN + 8); i += 256) ((short*)h_st)[i] = 0;
  for (int i = tid; i < 16 * 88; i += 256) ((short*)inp_bf)[i] = 0;
  for (int i = tid; i < 16 * 68; i += 256) ((float*)inp_f)[i] = 0.f;

  // ---- init rendezvous: barrier -> probe -> vote -> epoch broadcast ----
  {
    const unsigned* a = xa + g * 32 + (lane & 31);
    while (__hip_atomic_load(a, __ATOMIC_RELAXED, __HIP_MEMORY_SCOPE_SYSTEM) == 0)
      __builtin_amdgcn_s_sleep(2);
  }
  if (tid < 64) {  // wave 0: can we see all 32 group markers via sc0 (L2)?
    const unsigned* pp = pw + g * 32 + (lane & 31);
    int okp = 0;
    for (int it = 0; it < 64; ++it) {
      unsigned v;
      asm volatile("global_load_dword %0, %1, off sc0" : "=v"(v) : "v"(pp) : "memory");
      asm volatile("s_waitcnt vmcnt(0)" ::: "memory");
      __builtin_amdgcn_sched_barrier(0);
      if (__ballot(v == 0) == 0ull) { okp = 1; break; }
      __builtin_amdgcn_s_sleep(2);
    }
    if (lane == 0)
      __hip_atomic_store(vt + g * 32 + blockj, okp ? 1u : 2u,
                         __ATOMIC_RELAXED, __HIP_MEMORY_SCOPE_SYSTEM);
  }
  bool fast;
  {
    const unsigned* vv = vt + g * 32 + (lane & 31);
    unsigned mv;
    while ((mv = __hip_atomic_load(vv, __ATOMIC_RELAXED,
                                   __HIP_MEMORY_SCOPE_SYSTEM)) == 0)
      __builtin_amdgcn_s_sleep(2);
    fast = (__ballot(mv != 1u) == 0ull);
  }
  unsigned tag_hi;
  {
    ull e;
    while (((e = __hip_atomic_load(ebc, __ATOMIC_RELAXED,
                                   __HIP_MEMORY_SCOPE_SYSTEM)) & 1ull) == 0)
      __builtin_amdgcn_s_sleep(2);
    tag_hi = (unsigned)((e >> 1) << 10);  // epoch*1024; tg<=512 -> monotone
  }

  ull* hb_g[2] = {hb + (size_t)g * HBU, hb + (size_t)(GROUPS + g) * HBU};
  unsigned* dgg = dg + g;

  // X prefetch registers (rows 0..7 covered by threads 0..127)
  const int xrow = tid >> 4, xd0 = (tid & 15) * 4;
  float xp[4];
  if (tid < 128 && 0 < gtv) {
    const float* xr = X + ((size_t)(g * MB + xrow) * TSEQ + 0) * INDIM;
#pragma unroll
    for (int e = 0; e < 4; ++e) xp[e] = (xd0 + e < INDIM) ? xr[xd0 + e] : 0.f;
  }

  for (int t = 0; t < TSEQ; ++t) {
    const unsigned tagv = tag_hi + (unsigned)(t + 1);
    const bool teach = ((t % period) < gtv);
    if (teach && tid < 128) {
#pragma unroll
      for (int e = 0; e < 4; ++e) {
        inp_f[xrow][xd0 + e] = xp[e];
        inp_bf[xrow][xd0 + e] = f2bf(xp[e]);
      }
    }
    __syncthreads();  // S1: inp ready; h_st holds h(t-1)

    ffrag4 ghr0, ghr1;
    float hp0[4], hp1[4];
    if (w < 3) {
      ffrag4 A0[2], A1[2];
#pragma unroll
      for (int e = 0; e < 4; ++e) {
        A0[0][e] = bias0; A0[1][e] = 0.f;
        A1[0][e] = bias1; A1[1][e] = 0.f;
      }
#pragma unroll
      for (int ks = 0; ks < 32; ++ks) {
        const bfrag8 a = *(const bfrag8*)&h_st[c][ks * 32 + quad * 8];
        A0[ks & 1] = MFMA_B16(a, wB0[ks], A0[ks & 1]);
        A1[ks & 1] = MFMA_B16(a, wB1[ks], A1[ks & 1]);
      }
      ffrag4 g0 = A0[0] + A0[1], g1 = A1[0] + A1[1];
      if (w == 1) {
#pragma unroll
        for (int i = 0; i < 4; ++i) {
          gt_z[0][quad*4+i][c] = g0[i]; gt_z[1][quad*4+i][c] = g1[i];
        }
      } else if (w == 2) {
#pragma unroll
        for (int i = 0; i < 4; ++i) {
          gt_hn[0][quad*4+i][c] = g0[i]; gt_hn[1][quad*4+i][c] = g1[i];
        }
      } else {
        ghr0 = g0; ghr1 = g1;
#pragma unroll
        for (int i = 0; i < 4; ++i) {
          hp0[i] = bf2f(h_st[quad*4+i][j0*16+c]);
          hp1[i] = bf2f(h_st[quad*4+i][j1*16+c]);
        }
      }
    } else {
      ffrag4 r0, z0, n0, r1, z1, n1;
#pragma unroll
      for (int e = 0; e < 4; ++e) {
        r0[e]=0.f; z0[e]=0.f; n0[e]=bias0;
        r1[e]=0.f; z1[e]=0.f; n1[e]=bias1;
      }
#pragma unroll
      for (int ks = 0; ks < 2; ++ks) {
        const bfrag8 a = *(const bfrag8*)&inp_bf[c][ks * 32 + quad * 8];
        r0 = MFMA_B16(a, wB0[0+ks], r0); z0 = MFMA_B16(a, wB0[2+ks], z0);
        n0 = MFMA_B16(a, wB0[4+ks], n0);
        r1 = MFMA_B16(a, wB1[0+ks], r1); z1 = MFMA_B16(a, wB1[2+ks], z1);
        n1 = MFMA_B16(a, wB1[4+ks], n1);
      }
#pragma unroll
      for (int i = 0; i < 4; ++i) {
        gt_ir[0][quad*4+i][c] = r0[i]; gt_iz[0][quad*4+i][c] = z0[i];
        gt_in[0][quad*4+i][c] = n0[i];
        gt_ir[1][quad*4+i][c] = r1[i]; gt_iz[1][quad*4+i][c] = z1[i];
        gt_in[1][quad*4+i][c] = n1[i];
      }
    }
    __syncthreads();  // S2: gate tiles ready; h_st dead until gather refill

    ull* hw = hb_g[t & 1];
    u32x2 pub0, pub1;
    ull *dst0 = hw, *dst1 = hw;
    if (w == 0) {
#pragma unroll
      for (int i = 0; i < 4; ++i) {
        const int row = quad * 4 + i;
        float r = 1.f / (1.f + __expf(-(ghr0[i] + gt_ir[0][row][c])));
        float z = 1.f / (1.f + __expf(-(gt_z[0][row][c] + gt_iz[0][row][c])));
        float n = tanhf(gt_in[0][row][c] + r * gt_hn[0][row][c]);
        htmp[0][row][c] = f2bf((1.f - z) * n + z * hp0[i]);
        r = 1.f / (1.f + __expf(-(ghr1[i] + gt_ir[1][row][c])));
        z = 1.f / (1.f + __expf(-(gt_z[1][row][c] + gt_iz[1][row][c])));
        n = tanhf(gt_in[1][row][c] + r * gt_hn[1][row][c]);
        htmp[1][row][c] = f2bf((1.f - z) * n + z * hp1[i]);
      }
      asm volatile("" ::: "memory");
      const int r = lane >> 3, q = lane & 7;  // 8 rows x 8 col-pairs
      pub0[0] = (unsigned)(unsigned short)htmp[0][r][2*q] |
                ((unsigned)(unsigned short)htmp[0][r][2*q+1] << 16);
      pub0[1] = tagv;
      pub1[0] = (unsigned)(unsigned short)htmp[1][r][2*q] |
                ((unsigned)(unsigned short)htmp[1][r][2*q+1] << 16);
      pub1[1] = tagv;
      dst0 = hw + r * 512 + j0 * 8 + q;
      dst1 = hw + r * 512 + j1 * 8 + q;
      if (fast) {
        asm volatile("global_store_dwordx2 %0, %1, off sc0" :: "v"(dst0), "v"(pub0) : "memory");
        asm volatile("global_store_dwordx2 %0, %1, off sc0" :: "v"(dst1), "v"(pub1) : "memory");
      } else {
        asm volatile("global_store_dwordx2 %0, %1, off sc0 sc1" :: "v"(dst0), "v"(pub0) : "memory");
        asm volatile("global_store_dwordx2 %0, %1, off sc0 sc1" :: "v"(dst1), "v"(pub1) : "memory");
      }
    }

    // X(t+1) loads fly during the exchange window
    if (tid < 128) {
      const int tn = t + 1;
      if (tn < TSEQ && ((tn % period) < gtv)) {
        const float* xr = X + ((size_t)(g * MB + xrow) * TSEQ + tn) * INDIM;
#pragma unroll
        for (int e = 0; e < 4; ++e) xp[e] = (xd0 + e < INDIM) ? xr[xd0 + e] : 0.f;
      }
    }

    // gather h(t): 8 chunks x 16B per thread; each 8B unit self-validates
    // (payload | epoch-tag). Optimistic + per-chunk retry; valve -> MALL.
    {
      const unsigned* gp = (const unsigned*)hw + (size_t)tid * 4;  // dwords
      u32x4 v[8];
#pragma unroll
      for (int m = 0; m < 8; ++m) {
        const unsigned* a = gp + m * 1024;
        if (fast) { asm volatile("global_load_dwordx4 %0, %1, off sc0" : "=v"(v[m]) : "v"(a) : "memory"); }
        else      { asm volatile("global_load_dwordx4 %0, %1, off sc0 sc1" : "=v"(v[m]) : "v"(a) : "memory"); }
      }
      asm volatile("s_waitcnt vmcnt(0)" ::: "memory");
      __builtin_amdgcn_sched_barrier(0);
      unsigned bad = 0;
#pragma unroll
      for (int m = 0; m < 8; ++m)
        if (v[m][1] != tagv || v[m][3] != tagv) bad |= (1u << m);
      int rounds = 0;
      while (__ballot(bad != 0)) {
        __builtin_amdgcn_s_sleep(1);
        ++rounds;
        if ((rounds & 255) == 0) {  // degrade valve (perf-safety)
          unsigned dv = __hip_atomic_load(dgg, __ATOMIC_RELAXED,
                                          __HIP_MEMORY_SCOPE_SYSTEM);
          if (fast && (dv || rounds >= 4096)) {
            __hip_atomic_store(dgg, 1u, __ATOMIC_RELAXED, __HIP_MEMORY_SCOPE_SYSTEM);
            fast = false;
            if (w == 0) {  // republish this step via MALL
              asm volatile("global_store_dwordx2 %0, %1, off sc0 sc1" :: "v"(dst0), "v"(pub0) : "memory");
              asm volatile("global_store_dwordx2 %0, %1, off sc0 sc1" :: "v"(dst1), "v"(pub1) : "memory");
              asm volatile("s_waitcnt vmcnt(0)" ::: "memory");
            }
          }
        }
        // degraded mode alternates L2/MALL reads so data is found wherever
        // it lives (closes the mixed-mode stall window)
        const bool usem = (!fast) && (rounds & 1);
#pragma unroll
        for (int m = 0; m < 8; ++m) {
          if (__ballot((bad >> m) & 1u)) {
            const unsigned* a = gp + m * 1024;
            if (usem) { asm volatile("global_load_dwordx4 %0, %1, off sc0 sc1" : "=v"(v[m]) : "v"(a) : "memory"); }
            else      { asm volatile("global_load_dwordx4 %0, %1, off sc0" : "=v"(v[m]) : "v"(a) : "memory"); }
          }
        }
        asm volatile("s_waitcnt vmcnt(0)" ::: "memory");
        __builtin_amdgcn_sched_barrier(0);
        bad = 0;
#pragma unroll
        for (int m = 0; m < 8; ++m)
          if (v[m][1] != tagv || v[m][3] != tagv) bad |= (1u << m);
      }
#pragma unroll
      for (int m = 0; m < 8; ++m) {  // chunk m = row m, cols 4*tid..4*tid+3
        u32x2 pp; pp[0] = v[m][0]; pp[1] = v[m][2];
        *(u32x2*)&h_st[m][4 * tid] = pp;
      }
    }
    __syncthreads();  // S3: h_st = h(t)

    // out(t) = inp(t) + h(t) @ Wp^T + bp; round-robin writer block
    const int wj = t & 31;
    const bool rep = (t + 1 < TSEQ) && !(((t + 1) % period) < gtv);
    if (rep || blockj == wj) {
      ffrag4 oa0, oa1;
#pragma unroll
      for (int e = 0; e < 4; ++e) { oa0[e] = bp_l; oa1[e] = 0.f; }
#pragma unroll
      for (int ks = 0; ks < 32; ++ks) {
        const bfrag8 a = *(const bfrag8*)&h_st[c][ks * 32 + quad * 8];
        if (ks & 1) oa1 = MFMA_B16(a, wp[ks], oa1);
        else        oa0 = MFMA_B16(a, wp[ks], oa0);
      }
      ffrag4 o = oa0 + oa1;
#pragma unroll
      for (int i = 0; i < 4; ++i) {
        const int row = quad * 4 + i;
        if (dd < INDIM) {
          float val = o[i] + inp_f[row][dd];
          if (blockj == wj && row < MB)
            OUT[((size_t)(g * MB + row) * TSEQ + t) * INDIM + dd] = val;
          if (rep) { inp_f[row][dd] = val; inp_bf[row][dd] = f2bf(val); }
        } else if (rep) {
          inp_bf[row][dd] = 0;
        }
      }
    }
    // loop-head S1 orders inp writes vs next gi reads
  }
}

// ---------------- host ----------------

extern "C" void kernel_launch(void* const* d_in, const int* in_sizes, int n_in,
                              void* d_out, int out_size, void* d_ws, size_t ws_size,
                              hipStream_t stream) {
  const float* X    = (const float*)d_in[0];
  const float* W_ih = (const float*)d_in[1];
  const float* W_hh = (const float*)d_in[2];
  const float* b_ih = (const float*)d_in[3];
  const float* b_hh = (const float*)d_in[4];
  const float* W1   = (const float*)d_in[5];
  const float* b1   = (const float*)d_in[6];
  const float* W2   = (const float*)d_in[7];
  const float* b2   = (const float*)d_in[8];
  const float* W3   = (const float*)d_in[9];
  const float* b3   = (const float*)d_in[10];
  const int* pCL    = (const int*)d_in[11];
  const int* pGT    = (const int*)d_in[12];
  float* OUT = (float*)d_out;

  // layout (bytes):
  //   1024: bp | 2048: t1 | 8192: Wp (258048)
  //   270336: hb [2][8][4096] x 8B = 512 KB (head aliases T2 scratch, which
  //           is dead before the memset) -> ends 794624
  //   794624: ctrl 4 KB (bytes [0,4080) memset; epoch u64 at +4080 persists)
  char* ws = (char*)d_ws;
  float* bp = (float*)(ws + 1024);
  float* t1 = (float*)(ws + 2048);
  float* Wp = (float*)(ws + 8192);
  float* T2 = (float*)(ws + 270336);
  ull*   hb = (ull*)(ws + 270336);
  unsigned* ctrl = (unsigned*)(ws + 794624);
  if (ws_size < 795 * 1024) return;

  k_t1<<<256, 256, 0, stream>>>(W2, b1, b2, t1);
  k_gemm<<<dim3(64, 4), dim3(16, 16), 0, stream>>>(W3, W2, T2, INDIM, HIDDEN, HIDDEN);
  k_gemm<<<dim3(64, 4), dim3(16, 16), 0, stream>>>(T2, W1, Wp, INDIM, HIDDEN, HIDDEN);
  k_bp<<<1, 256, 0, stream>>>(W3, t1, b3, bp);
  hipMemsetAsync(hb, 0, (size_t)2 * GROUPS * HBU * 8, stream);  // tags := 0
  hipMemsetAsync(ctrl, 0, 4080, stream);  // probe/barrier/votes/dg/ebc := 0
  k_main<<<256, 256, 0, stream>>>(X, W_ih, W_hh, b_ih, b_hh, Wp, bp, pCL, pGT,
                                  ctrl, hb, OUT);
}

// Round 8
// 5993.644 us; speedup vs baseline: 2.1270x; 1.0085x over previous
//
#include <hip/hip_runtime.h>
#include <hip/hip_bf16.h>

// Collapsed-projector persistent-GRU kernel for MI355X.
// Round 14: XCD-local h-exchange, minimal deterministic variant.
// Base = R12 skeleton (compiled, ran, passed correctness). Changes:
//  (1) purity oracle = HW_REG_XCC_ID (deterministic, write-once table;
//      verdict "all 32 group ids equal" is a pure function -> all blocks
//      agree, no vote phase). Garbage ids -> impure -> MALL fallback.
//  (2) degraded-mode reads ALWAYS sc0 sc1 (fixes R12's stale-reader-L2
//      infinite retry -> removes 37ms outliers).
//  (3) valve republishes via MALL on transition + every 4096 rounds
//      (bounds the dirty-line-stranded-in-writer-L2 case).
// Fixed mapping g=bid&7, blockj=bid>>3 (no dynamic assignment, no global
// 256-entry rendezvous). Epoch tags (persistent counter) keep stale L2
// lines from any previous launch/replay non-validating.

#define HIDDEN 1024
#define INDIM  63
#define TSEQ   512
#define MB     8
#define GROUPS 8
#define HBU    4096   // 8B units per (parity,group): 8 rows x 512 col-pairs

typedef __attribute__((ext_vector_type(8))) short bfrag8;  // 8 bf16 in 4 VGPRs
typedef __attribute__((ext_vector_type(4))) float ffrag4;  // MFMA accumulator
typedef __attribute__((ext_vector_type(4))) unsigned u32x4;
typedef __attribute__((ext_vector_type(2))) unsigned u32x2;
typedef unsigned long long ull;

#define MFMA_B16(a, b, c) __builtin_amdgcn_mfma_f32_16x16x32_bf16((a), (b), (c), 0, 0, 0)

__device__ __forceinline__ short f2bf(float x) {
  __hip_bfloat16 b = __float2bfloat16(x);
  return __builtin_bit_cast(short, b);
}
__device__ __forceinline__ float bf2f(short s) {
  unsigned u = ((unsigned)(unsigned short)s) << 16;
  return __builtin_bit_cast(float, u);
}

// ---------------- precompute kernels ----------------

__global__ void k_t1(const float* __restrict__ W2, const float* __restrict__ b1,
                     const float* __restrict__ b2, float* __restrict__ t1) {
  const int w = threadIdx.x >> 6, lane = threadIdx.x & 63;
  const int o = blockIdx.x * 4 + w;
  if (o >= HIDDEN) return;
  const float* row = W2 + (size_t)o * HIDDEN;
  float s = 0.f;
  for (int k = lane; k < HIDDEN; k += 64) s += row[k] * b1[k];
  for (int off = 32; off; off >>= 1) s += __shfl_down(s, off, 64);
  if (lane == 0) t1[o] = s + b2[o];
}

__global__ void k_bp(const float* __restrict__ W3, const float* __restrict__ t1,
                     const float* __restrict__ b3, float* __restrict__ bp) {
  const int w = threadIdx.x >> 6, lane = threadIdx.x & 63;
  for (int d = w; d < INDIM; d += 4) {
    const float* row = W3 + (size_t)d * HIDDEN;
    float s = 0.f;
    for (int k = lane; k < HIDDEN; k += 64) s += row[k] * t1[k];
    for (int off = 32; off; off >>= 1) s += __shfl_down(s, off, 64);
    if (lane == 0) bp[d] = s + b3[d];
  }
}

__global__ void k_gemm(const float* __restrict__ A, const float* __restrict__ B,
                       float* __restrict__ C, int M, int N, int K) {
  __shared__ float As[16][17], Bs[16][17];
  const int tx = threadIdx.x, ty = threadIdx.y;
  const int row = blockIdx.y * 16 + ty;
  const int col = blockIdx.x * 16 + tx;
  float acc = 0.f;
  for (int k0 = 0; k0 < K; k0 += 16) {
    As[ty][tx] = (row < M) ? A[(size_t)row * K + k0 + tx] : 0.f;
    Bs[ty][tx] = B[(size_t)(k0 + ty) * N + col];
    __syncthreads();
#pragma unroll
    for (int kk = 0; kk < 16; ++kk) acc += As[ty][kk] * Bs[kk][tx];
    __syncthreads();
  }
  if (row < M && col < N) C[(size_t)row * N + col] = acc;
}

// ---------------- main persistent kernel ----------------

__global__ __launch_bounds__(256, 1) void k_main(
    const float* __restrict__ X,
    const float* __restrict__ W_ih, const float* __restrict__ W_hh,
    const float* __restrict__ b_ih, const float* __restrict__ b_hh,
    const float* __restrict__ WpF, const float* __restrict__ bpF,
    const int* __restrict__ pCL, const int* __restrict__ pGT,
    unsigned* __restrict__ ctrl, ull* __restrict__ hb,
    float* __restrict__ OUT) {
  __shared__ short h_st[16][HIDDEN + 8];   // rows 8..15 stay zero (MB=8)
  __shared__ short inp_bf[16][88];
  __shared__ float inp_f[16][68];
  __shared__ float gt_z[2][16][20], gt_hn[2][16][20];
  __shared__ float gt_ir[2][16][20], gt_iz[2][16][20], gt_in[2][16][20];
  __shared__ short htmp[2][16][20];
  __shared__ unsigned sh_fast;

  const int tid = threadIdx.x;
  const int w = tid >> 6, lane = tid & 63;
  const int c = lane & 15, quad = lane >> 4;
  const int bid = blockIdx.x;
  const int g = bid & 7;           // fixed mapping (round-robin XCD hint)
  const int blockj = bid >> 3;     // 0..31
  const int j0 = blockj * 2, j1 = j0 + 1;

  // ctrl carve (dwords; bytes [0,2048) memset each launch; epoch NOT)
  unsigned* xarr = ctrl;                // [256] published XCC ids (|0x100)
  unsigned* dg   = ctrl + 256;          // [8] degrade flags
  ull* ebc       = (ull*)(ctrl + 264);  // epoch broadcast
  ull* epoch     = (ull*)(ctrl + 1020); // persistent counter (byte 4080)

  // ---- publish my XCC id; bid 0 also bumps+broadcasts the epoch ----
  if (tid == 0) {
    unsigned x;
    asm volatile("s_getreg_b32 %0, hwreg(HW_REG_XCC_ID)" : "=s"(x));
    __hip_atomic_store(&xarr[bid], 0x100u | (x & 7u), __ATOMIC_RELAXED,
                       __HIP_MEMORY_SCOPE_SYSTEM);
    if (bid == 0) {
      ull e = __hip_atomic_fetch_add(epoch, 1ull, __ATOMIC_RELAXED,
                                     __HIP_MEMORY_SCOPE_SYSTEM);
      __hip_atomic_store(ebc, (e << 1) | 1ull, __ATOMIC_RELAXED,
                         __HIP_MEMORY_SCOPE_SYSTEM);
    }
    sh_fast = 0u;
  }

  const int gtv = pGT[0];
  int period = pCL[0] + gtv;
  if (period < 1) period = 1;

  // --- persistent register-resident weights: TWO col-slices per block ---
  bfrag8 wB0[32], wB1[32], wp[32];
  if (w < 3) {
    const float* wr0 = W_hh + ((size_t)w * HIDDEN + (size_t)j0 * 16 + c) * HIDDEN;
    const float* wr1 = W_hh + ((size_t)w * HIDDEN + (size_t)j1 * 16 + c) * HIDDEN;
#pragma unroll
    for (int ks = 0; ks < 32; ++ks) {
      bfrag8 f0, f1;
#pragma unroll
      for (int e = 0; e < 8; ++e) {
        f0[e] = f2bf(wr0[ks * 32 + quad * 8 + e]);
        f1[e] = f2bf(wr1[ks * 32 + quad * 8 + e]);
      }
      wB0[ks] = f0; wB1[ks] = f1;
    }
  } else {
#pragma unroll
    for (int gate = 0; gate < 3; ++gate) {
      const float* wr0 = W_ih + ((size_t)gate * HIDDEN + (size_t)j0 * 16 + c) * INDIM;
      const float* wr1 = W_ih + ((size_t)gate * HIDDEN + (size_t)j1 * 16 + c) * INDIM;
#pragma unroll
      for (int ks = 0; ks < 2; ++ks) {
        bfrag8 f0, f1;
#pragma unroll
        for (int e = 0; e < 8; ++e) {
          int k = ks * 32 + quad * 8 + e;
          f0[e] = (k < INDIM) ? f2bf(wr0[k]) : (short)0;
          f1[e] = (k < INDIM) ? f2bf(wr1[k]) : (short)0;
        }
        wB0[gate * 2 + ks] = f0; wB1[gate * 2 + ks] = f1;
      }
    }
  }
  const int dd = 16 * w + c;
  {
    const float* wr = WpF + (size_t)dd * HIDDEN;
#pragma unroll
    for (int ks = 0; ks < 32; ++ks) {
      bfrag8 f;
#pragma unroll
      for (int e = 0; e < 8; ++e)
        f[e] = (dd < INDIM) ? f2bf(wr[ks * 32 + quad * 8 + e]) : (short)0;
      wp[ks] = f;
    }
  }

  float bias0, bias1;
  if (w == 0)      { bias0 = b_ih[j0*16+c] + b_hh[j0*16+c];
                     bias1 = b_ih[j1*16+c] + b_hh[j1*16+c]; }
  else if (w == 1) { bias0 = b_ih[HIDDEN + j0*16+c] + b_hh[HIDDEN + j0*16+c];
                     bias1 = b_ih[HIDDEN + j1*16+c] + b_hh[HIDDEN + j1*16+c]; }
  else if (w == 2) { bias0 = b_hh[2*HIDDEN + j0*16+c];
                     bias1 = b_hh[2*HIDDEN + j1*16+c]; }
  else             { bias0 = b_ih[2*HIDDEN + j0*16+c];
                     bias1 = b_ih[2*HIDDEN + j1*16+c]; }
  const float bp_l = (dd < INDIM) ? bpF[dd] : 0.f;

  for (int i = tid; i < 16 * (HIDDEN + 8); i += 256) ((short*)h_st)[i] = 0;
  for (int i = tid; i < 16 * 88; i += 256) ((short*)inp_bf)[i] = 0;
  for (int i = tid; i < 16 * 68; i += 256) ((float*)inp_f)[i] = 0.f;

  // ---- purity verdict: poll MY GROUP's 32 write-once id entries ----
  // group members are bids {blockj'*8 + g}. Verdict "all ids equal" is a
  // pure function of write-once data -> every block of the group agrees.
  // Bounded poll; timeout -> impure (valve converges any inconsistency).
  if (w == 0) {
    const unsigned* pa = xarr + (lane & 31) * 8 + g;
    unsigned v = 0;
    bool seen = false;
    for (int it = 0; it < (1 << 20); ++it) {
      asm volatile("global_load_dword %0, %1, off sc0 sc1"
                   : "=v"(v) : "v"(pa) : "memory");
      asm volatile("s_waitcnt vmcnt(0)" ::: "memory");
      __builtin_amdgcn_sched_barrier(0);
      if (__ballot((v & 0x100u) == 0u) == 0ull) { seen = true; break; }
      __builtin_amdgcn_s_sleep(2);
    }
    unsigned ref = __builtin_amdgcn_readfirstlane(v);
    const bool allEq = seen && (__ballot(v != ref) == 0ull);
    if (lane == 0) sh_fast = allEq ? 1u : 0u;
  }
  __syncthreads();
  bool fast = (sh_fast != 0u);

  unsigned tag_hi;
  {
    ull e;
    while (((e = __hip_atomic_load(ebc, __ATOMIC_RELAXED,
                                   __HIP_MEMORY_SCOPE_SYSTEM)) & 1ull) == 0)
      __builtin_amdgcn_s_sleep(2);
    tag_hi = (unsigned)((e >> 1) << 10);  // epoch*1024; tg<=512 -> monotone
  }

  ull* hb_g[2] = {hb + (size_t)g * HBU, hb + (size_t)(GROUPS + g) * HBU};
  unsigned* dgg = dg + g;

  // X prefetch registers (rows 0..7 covered by threads 0..127)
  const int xrow = tid >> 4, xd0 = (tid & 15) * 4;
  float xp[4];
  if (tid < 128 && 0 < gtv) {
    const float* xr = X + ((size_t)(g * MB + xrow) * TSEQ + 0) * INDIM;
#pragma unroll
    for (int e = 0; e < 4; ++e) xp[e] = (xd0 + e < INDIM) ? xr[xd0 + e] : 0.f;
  }

  for (int t = 0; t < TSEQ; ++t) {
    const unsigned tagv = tag_hi + (unsigned)(t + 1);
    const bool teach = ((t % period) < gtv);
    if (teach && tid < 128) {
#pragma unroll
      for (int e = 0; e < 4; ++e) {
        inp_f[xrow][xd0 + e] = xp[e];
        inp_bf[xrow][xd0 + e] = f2bf(xp[e]);
      }
    }
    __syncthreads();  // S1: inp ready; h_st holds h(t-1)

    ffrag4 ghr0, ghr1;
    float hp0[4], hp1[4];
    if (w < 3) {
      ffrag4 A0[2], A1[2];
#pragma unroll
      for (int e = 0; e < 4; ++e) {
        A0[0][e] = bias0; A0[1][e] = 0.f;
        A1[0][e] = bias1; A1[1][e] = 0.f;
      }
#pragma unroll
      for (int ks = 0; ks < 32; ++ks) {
        const bfrag8 a = *(const bfrag8*)&h_st[c][ks * 32 + quad * 8];
        A0[ks & 1] = MFMA_B16(a, wB0[ks], A0[ks & 1]);
        A1[ks & 1] = MFMA_B16(a, wB1[ks], A1[ks & 1]);
      }
      ffrag4 g0 = A0[0] + A0[1], g1 = A1[0] + A1[1];
      if (w == 1) {
#pragma unroll
        for (int i = 0; i < 4; ++i) {
          gt_z[0][quad*4+i][c] = g0[i]; gt_z[1][quad*4+i][c] = g1[i];
        }
      } else if (w == 2) {
#pragma unroll
        for (int i = 0; i < 4; ++i) {
          gt_hn[0][quad*4+i][c] = g0[i]; gt_hn[1][quad*4+i][c] = g1[i];
        }
      } else {
        ghr0 = g0; ghr1 = g1;
#pragma unroll
        for (int i = 0; i < 4; ++i) {
          hp0[i] = bf2f(h_st[quad*4+i][j0*16+c]);
          hp1[i] = bf2f(h_st[quad*4+i][j1*16+c]);
        }
      }
    } else {
      ffrag4 r0, z0, n0, r1, z1, n1;
#pragma unroll
      for (int e = 0; e < 4; ++e) {
        r0[e]=0.f; z0[e]=0.f; n0[e]=bias0;
        r1[e]=0.f; z1[e]=0.f; n1[e]=bias1;
      }
#pragma unroll
      for (int ks = 0; ks < 2; ++ks) {
        const bfrag8 a = *(const bfrag8*)&inp_bf[c][ks * 32 + quad * 8];
        r0 = MFMA_B16(a, wB0[0+ks], r0); z0 = MFMA_B16(a, wB0[2+ks], z0);
        n0 = MFMA_B16(a, wB0[4+ks], n0);
        r1 = MFMA_B16(a, wB1[0+ks], r1); z1 = MFMA_B16(a, wB1[2+ks], z1);
        n1 = MFMA_B16(a, wB1[4+ks], n1);
      }
#pragma unroll
      for (int i = 0; i < 4; ++i) {
        gt_ir[0][quad*4+i][c] = r0[i]; gt_iz[0][quad*4+i][c] = z0[i];
        gt_in[0][quad*4+i][c] = n0[i];
        gt_ir[1][quad*4+i][c] = r1[i]; gt_iz[1][quad*4+i][c] = z1[i];
        gt_in[1][quad*4+i][c] = n1[i];
      }
    }
    __syncthreads();  // S2: gate tiles ready; h_st dead until gather refill

    ull* hw = hb_g[t & 1];
    u32x2 pub0, pub1;
    ull *dst0 = hw, *dst1 = hw;
    if (w == 0) {
#pragma unroll
      for (int i = 0; i < 4; ++i) {
        const int row = quad * 4 + i;
        float r = 1.f / (1.f + __expf(-(ghr0[i] + gt_ir[0][row][c])));
        float z = 1.f / (1.f + __expf(-(gt_z[0][row][c] + gt_iz[0][row][c])));
        float n = tanhf(gt_in[0][row][c] + r * gt_hn[0][row][c]);
        htmp[0][row][c] = f2bf((1.f - z) * n + z * hp0[i]);
        r = 1.f / (1.f + __expf(-(ghr1[i] + gt_ir[1][row][c])));
        z = 1.f / (1.f + __expf(-(gt_z[1][row][c] + gt_iz[1][row][c])));
        n = tanhf(gt_in[1][row][c] + r * gt_hn[1][row][c]);
        htmp[1][row][c] = f2bf((1.f - z) * n + z * hp1[i]);
      }
      asm volatile("" ::: "memory");
      const int r = lane >> 3, q = lane & 7;  // 8 rows x 8 col-pairs
      pub0[0] = (unsigned)(unsigned short)htmp[0][r][2*q] |
                ((unsigned)(unsigned short)htmp[0][r][2*q+1] << 16);
      pub0[1] = tagv;
      pub1[0] = (unsigned)(unsigned short)htmp[1][r][2*q] |
                ((unsigned)(unsigned short)htmp[1][r][2*q+1] << 16);
      pub1[1] = tagv;
      dst0 = hw + r * 512 + j0 * 8 + q;
      dst1 = hw + r * 512 + j1 * 8 + q;
      if (fast) {
        asm volatile("global_store_dwordx2 %0, %1, off sc0" :: "v"(dst0), "v"(pub0) : "memory");
        asm volatile("global_store_dwordx2 %0, %1, off sc0" :: "v"(dst1), "v"(pub1) : "memory");
      } else {
        asm volatile("global_store_dwordx2 %0, %1, off sc0 sc1" :: "v"(dst0), "v"(pub0) : "memory");
        asm volatile("global_store_dwordx2 %0, %1, off sc0 sc1" :: "v"(dst1), "v"(pub1) : "memory");
      }
    }

    // X(t+1) loads fly during the exchange window
    if (tid < 128) {
      const int tn = t + 1;
      if (tn < TSEQ && ((tn % period) < gtv)) {
        const float* xr = X + ((size_t)(g * MB + xrow) * TSEQ + tn) * INDIM;
#pragma unroll
        for (int e = 0; e < 4; ++e) xp[e] = (xd0 + e < INDIM) ? xr[xd0 + e] : 0.f;
      }
    }

    // gather h(t): 8 chunks x 16B per thread; each 8B unit self-validates
    // (payload | epoch-tag). Optimistic + per-chunk retry; valve -> MALL.
    {
      const unsigned* gp = (const unsigned*)hw + (size_t)tid * 4;  // dwords
      u32x4 v[8];
#pragma unroll
      for (int m = 0; m < 8; ++m) {
        const unsigned* a = gp + m * 1024;
        if (fast) { asm volatile("global_load_dwordx4 %0, %1, off sc0" : "=v"(v[m]) : "v"(a) : "memory"); }
        else      { asm volatile("global_load_dwordx4 %0, %1, off sc0 sc1" : "=v"(v[m]) : "v"(a) : "memory"); }
      }
      asm volatile("s_waitcnt vmcnt(0)" ::: "memory");
      __builtin_amdgcn_sched_barrier(0);
      unsigned bad = 0;
#pragma unroll
      for (int m = 0; m < 8; ++m)
        if (v[m][1] != tagv || v[m][3] != tagv) bad |= (1u << m);
      int rounds = 0;
      while (__ballot(bad != 0)) {
        __builtin_amdgcn_s_sleep(1);
        ++rounds;
        if ((rounds & 255) == 0) {  // degrade valve (perf-safety only)
          unsigned dv = __hip_atomic_load(dgg, __ATOMIC_RELAXED,
                                          __HIP_MEMORY_SCOPE_SYSTEM);
          if (dv || rounds >= 4096) {
            const bool transition = fast;
            if (fast) {
              __hip_atomic_store(dgg, 1u, __ATOMIC_RELAXED,
                                 __HIP_MEMORY_SCOPE_SYSTEM);
              fast = false;
            }
            // republish via MALL on transition and every 4096 rounds
            // (covers dirty lines stranded in the writer's L2)
            if (w == 0 && (transition || (rounds & 4095) == 0)) {
              asm volatile("global_store_dwordx2 %0, %1, off sc0 sc1" :: "v"(dst0), "v"(pub0) : "memory");
              asm volatile("global_store_dwordx2 %0, %1, off sc0 sc1" :: "v"(dst1), "v"(pub1) : "memory");
              asm volatile("s_waitcnt vmcnt(0)" ::: "memory");
            }
          }
        }
        // reload stale chunks. fast: same-L2 sc0 (store and load hit the
        // SAME physical L2). degraded: ALWAYS sc0 sc1 (never re-read the
        // reader-L2 stale clean copy).
#pragma unroll
        for (int m = 0; m < 8; ++m) {
          if (__ballot((bad >> m) & 1u)) {
            const unsigned* a = gp + m * 1024;
            if (fast) { asm volatile("global_load_dwordx4 %0, %1, off sc0" : "=v"(v[m]) : "v"(a) : "memory"); }
            else      { asm volatile("global_load_dwordx4 %0, %1, off sc0 sc1" : "=v"(v[m]) : "v"(a) : "memory"); }
          }
        }
        asm volatile("s_waitcnt vmcnt(0)" ::: "memory");
        __builtin_amdgcn_sched_barrier(0);
        bad = 0;
#pragma unroll
        for (int m = 0; m < 8; ++m)
          if (v[m][1] != tagv || v[m][3] != tagv) bad |= (1u << m);
      }
#pragma unroll
      for (int m = 0; m < 8; ++m) {  // chunk m = row m, cols 4*tid..4*tid+3
        u32x2 pp; pp[0] = v[m][0]; pp[1] = v[m][2];
        *(u32x2*)&h_st[m][4 * tid] = pp;
      }
    }
    __syncthreads();  // S3: h_st = h(t)

    // out(t) = inp(t) + h(t) @ Wp^T + bp; round-robin writer block
    const int wj = t & 31;
    const bool rep = (t + 1 < TSEQ) && !(((t + 1) % period) < gtv);
    if (rep || blockj == wj) {
      ffrag4 oa0, oa1;
#pragma unroll
      for (int e = 0; e < 4; ++e) { oa0[e] = bp_l; oa1[e] = 0.f; }
#pragma unroll
      for (int ks = 0; ks < 32; ++ks) {
        const bfrag8 a = *(const bfrag8*)&h_st[c][ks * 32 + quad * 8];
        if (ks & 1) oa1 = MFMA_B16(a, wp[ks], oa1);
        else        oa0 = MFMA_B16(a, wp[ks], oa0);
      }
      ffrag4 o = oa0 + oa1;
#pragma unroll
      for (int i = 0; i < 4; ++i) {
        const int row = quad * 4 + i;
        if (dd < INDIM) {
          float val = o[i] + inp_f[row][dd];
          if (blockj == wj && row < MB)
            OUT[((size_t)(g * MB + row) * TSEQ + t) * INDIM + dd] = val;
          if (rep) { inp_f[row][dd] = val; inp_bf[row][dd] = f2bf(val); }
        } else if (rep) {
          inp_bf[row][dd] = 0;
        }
      }
    }
    // loop-head S1 orders inp writes vs next gi reads
  }
}

// ---------------- host ----------------

extern "C" void kernel_launch(void* const* d_in, const int* in_sizes, int n_in,
                              void* d_out, int out_size, void* d_ws, size_t ws_size,
                              hipStream_t stream) {
  const float* X    = (const float*)d_in[0];
  const float* W_ih = (const float*)d_in[1];
  const float* W_hh = (const float*)d_in[2];
  const float* b_ih = (const float*)d_in[3];
  const float* b_hh = (const float*)d_in[4];
  const float* W1   = (const float*)d_in[5];
  const float* b1   = (const float*)d_in[6];
  const float* W2   = (const float*)d_in[7];
  const float* b2   = (const float*)d_in[8];
  const float* W3   = (const float*)d_in[9];
  const float* b3   = (const float*)d_in[10];
  const int* pCL    = (const int*)d_in[11];
  const int* pGT    = (const int*)d_in[12];
  float* OUT = (float*)d_out;

  // layout (bytes):
  //   1024: bp | 2048: t1 | 8192: Wp (258048)
  //   270336: hb [2][8][4096] x 8B = 512 KB (head aliases T2 scratch, which
  //           is dead before the memset) -> ends 794624
  //   794624: ctrl 4 KB (bytes [0,2048) memset; epoch u64 at +4080 persists)
  char* ws = (char*)d_ws;
  float* bp = (float*)(ws + 1024);
  float* t1 = (float*)(ws + 2048);
  float* Wp = (float*)(ws + 8192);
  float* T2 = (float*)(ws + 270336);
  ull*   hb = (ull*)(ws + 270336);
  unsigned* ctrl = (unsigned*)(ws + 794624);
  if (ws_size < 795 * 1024) return;

  k_t1<<<256, 256, 0, stream>>>(W2, b1, b2, t1);
  k_gemm<<<dim3(64, 4), dim3(16, 16), 0, stream>>>(W3, W2, T2, INDIM, HIDDEN, HIDDEN);
  k_gemm<<<dim3(64, 4), dim3(16, 16), 0, stream>>>(T2, W1, Wp, INDIM, HIDDEN, HIDDEN);
  k_bp<<<1, 256, 0, stream>>>(W3, t1, b3, bp);
  hipMemsetAsync(hb, 0, (size_t)2 * GROUPS * HBU * 8, stream);  // tags := 0
  hipMemsetAsync(ctrl, 0, 2048, stream);  // xarr/dg/ebc := 0 (epoch persists)
  k_main<<<256, 256, 0, stream>>>(X, W_ih, W_hh, b_ih, b_hh, Wp, bp, pCL, pGT,
                                  ctrl, hb, OUT);
}

// Round 9
// 3352.954 us; speedup vs baseline: 3.8022x; 1.7876x over previous
//
#include <hip/hip_runtime.h>
#include <hip/hip_bf16.h>

// Collapsed-projector persistent-GRU kernel for MI355X.
// FINAL = Round 8 (best harness-verified: 3354 us overall, ~3240 us steady).
// Exchange: LDS pub_flag issue-gate, SYSTEM scope, self-consistent 4B tagged
// words ((tag16<<16)|bf16), 16B coherent gather loads, optimistic tag-retry.
// Session evidence (R8/R9/R10): three protocol variants with 2-3x different
// traffic/VALU all pin at 3.24-3.35 ms -> the floor is MALL store->load
// visibility latency x ~2-3 serialized hops/step + max-of-64 skew, not
// bandwidth, request count, or retry rate. XCD-local L2 variants (R11-R14)
// all measured worse (6-12.5 ms). This is the measured optimum.

#define HIDDEN 1024
#define INDIM  63
#define TSEQ   512
#define MB     16
#define NGRP   4
#define HB_DW  (MB * 1024)   // dwords per (parity, group) buffer = 64 KB

typedef __attribute__((ext_vector_type(8))) short bfrag8;  // 8 bf16 in 4 VGPRs
typedef __attribute__((ext_vector_type(4))) float ffrag4;  // MFMA accumulator
typedef __attribute__((ext_vector_type(4))) unsigned u32x4;
typedef unsigned long long ull;

#define MFMA_B16(a, b, c) __builtin_amdgcn_mfma_f32_16x16x32_bf16((a), (b), (c), 0, 0, 0)

// coherent 16B load (bypass L1/L2 -> LLC), rule-18 fencing done at call site
#define GLOAD4(dst, ptr) \
  asm volatile("global_load_dwordx4 %0, %1, off sc0 sc1" \
               : "=v"(dst) : "v"(ptr) : "memory")

__device__ __forceinline__ short f2bf(float x) {
  __hip_bfloat16 b = __float2bfloat16(x);
  return __builtin_bit_cast(short, b);
}
__device__ __forceinline__ float bf2f(short s) {
  unsigned u = ((unsigned)(unsigned short)s) << 16;
  return __builtin_bit_cast(float, u);
}

// ---------------- precompute kernels ----------------

__global__ void k_t1(const float* __restrict__ W2, const float* __restrict__ b1,
                     const float* __restrict__ b2, float* __restrict__ t1) {
  const int w = threadIdx.x >> 6, lane = threadIdx.x & 63;
  const int o = blockIdx.x * 4 + w;
  if (o >= HIDDEN) return;
  const float* row = W2 + (size_t)o * HIDDEN;
  float s = 0.f;
  for (int k = lane; k < HIDDEN; k += 64) s += row[k] * b1[k];
  for (int off = 32; off; off >>= 1) s += __shfl_down(s, off, 64);
  if (lane == 0) t1[o] = s + b2[o];
}

__global__ void k_bp(const float* __restrict__ W3, const float* __restrict__ t1,
                     const float* __restrict__ b3, float* __restrict__ bp) {
  const int w = threadIdx.x >> 6, lane = threadIdx.x & 63;
  for (int d = w; d < INDIM; d += 4) {
    const float* row = W3 + (size_t)d * HIDDEN;
    float s = 0.f;
    for (int k = lane; k < HIDDEN; k += 64) s += row[k] * t1[k];
    for (int off = 32; off; off >>= 1) s += __shfl_down(s, off, 64);
    if (lane == 0) bp[d] = s + b3[d];
  }
}

__global__ void k_gemm(const float* __restrict__ A, const float* __restrict__ B,
                       float* __restrict__ C, int M, int N, int K) {
  __shared__ float As[16][17], Bs[16][17];
  const int tx = threadIdx.x, ty = threadIdx.y;
  const int row = blockIdx.y * 16 + ty;
  const int col = blockIdx.x * 16 + tx;
  float acc = 0.f;
  for (int k0 = 0; k0 < K; k0 += 16) {
    As[ty][tx] = (row < M) ? A[(size_t)row * K + k0 + tx] : 0.f;
    Bs[ty][tx] = B[(size_t)(k0 + ty) * N + col];
    __syncthreads();
#pragma unroll
    for (int kk = 0; kk < 16; ++kk) acc += As[ty][kk] * Bs[kk][tx];
    __syncthreads();
  }
  if (row < M && col < N) C[(size_t)row * N + col] = acc;
}

// ---------------- main persistent kernel ----------------

__global__ __launch_bounds__(256, 1) void k_main(
    const float* __restrict__ X,
    const float* __restrict__ W_ih, const float* __restrict__ W_hh,
    const float* __restrict__ b_ih, const float* __restrict__ b_hh,
    const float* __restrict__ WpF, const float* __restrict__ bpF,
    const int* __restrict__ pCL, const int* __restrict__ pGT,
    unsigned* __restrict__ hb, float* __restrict__ OUT) {
  __shared__ short h_st[MB][HIDDEN + 8];   // staged h, row stride 2064B
  __shared__ short inp_bf[MB][88];
  __shared__ float inp_f[MB][68];
  // stride 20 words: bank = (16q + 20i + c) mod 32 -> uniform 2-way (free)
  __shared__ float gt_z[MB][20], gt_hn[MB][20];
  __shared__ float gt_ir[MB][20], gt_iz[MB][20], gt_in[MB][20];
  __shared__ short htmp[MB][20];           // h-slice repack for packed store
  __shared__ int pub_flag;                 // publish-issue gate (perf only)

  const int tid = threadIdx.x;
  const int w = tid >> 6;
  const int lane = tid & 63;
  const int c = lane & 15;
  const int quad = lane >> 4;
  const int g = blockIdx.x >> 6;
  const int j = blockIdx.x & 63;

  const int gtv = pGT[0];
  int period = pCL[0] + gtv;
  if (period < 1) period = 1;

  // --- persistent register-resident weight fragments ---
  bfrag8 wB[32];
  bfrag8 wp[32];
  if (w < 3) {
    const float* wr = W_hh + ((size_t)w * HIDDEN + (size_t)j * 16 + c) * HIDDEN;
#pragma unroll
    for (int ks = 0; ks < 32; ++ks) {
      const float* p = wr + ks * 32 + quad * 8;
      bfrag8 f;
#pragma unroll
      for (int e = 0; e < 8; ++e) f[e] = f2bf(p[e]);
      wB[ks] = f;
    }
  } else {
#pragma unroll
    for (int gate = 0; gate < 3; ++gate) {
      const float* wr = W_ih + ((size_t)gate * HIDDEN + (size_t)j * 16 + c) * INDIM;
#pragma unroll
      for (int ks = 0; ks < 2; ++ks) {
        bfrag8 f;
#pragma unroll
        for (int e = 0; e < 8; ++e) {
          int k = ks * 32 + quad * 8 + e;
          f[e] = (k < INDIM) ? f2bf(wr[k]) : (short)0;
        }
        wB[gate * 2 + ks] = f;
      }
    }
  }
  const int dd = 16 * w + c;
  {
    const float* wr = WpF + (size_t)dd * HIDDEN;
#pragma unroll
    for (int ks = 0; ks < 32; ++ks) {
      bfrag8 f;
#pragma unroll
      for (int e = 0; e < 8; ++e)
        f[e] = (dd < INDIM) ? f2bf(wr[ks * 32 + quad * 8 + e]) : (short)0;
      wp[ks] = f;
    }
  }

  float bias_g;
  if (w == 0)      bias_g = b_ih[j * 16 + c] + b_hh[j * 16 + c];
  else if (w == 1) bias_g = b_ih[HIDDEN + j * 16 + c] + b_hh[HIDDEN + j * 16 + c];
  else if (w == 2) bias_g = b_hh[2 * HIDDEN + j * 16 + c];
  else             bias_g = b_ih[2 * HIDDEN + j * 16 + c];
  const float bp_l = (dd < INDIM) ? bpF[dd] : 0.f;

  for (int i = tid; i < MB * (HIDDEN + 8); i += 256) ((short*)h_st)[i] = 0;
  for (int i = tid; i < MB * 88; i += 256) ((short*)inp_bf)[i] = 0;
  for (int i = tid; i < MB * 68; i += 256) ((float*)inp_f)[i] = 0.f;
  if (tid == 0) pub_flag = 0;

  // tagged h buffers: [2][NGRP][MB][1024] dwords, dword = (tag16<<16)|bf16
  unsigned* hb_g[2] = {hb + (size_t)g * HB_DW,
                       hb + (size_t)(NGRP + g) * HB_DW};

  // X prefetch (teacher-forcing rows) held in registers across iterations
  const int xrow = tid >> 4, xd0 = (tid & 15) * 4;
  float xp[4];
  if ((0 % period) < gtv) {
    const float* xr = X + ((size_t)(g * MB + xrow) * TSEQ + 0) * INDIM;
#pragma unroll
    for (int e = 0; e < 4; ++e) xp[e] = (xd0 + e < INDIM) ? xr[xd0 + e] : 0.f;
  }

  for (int t = 0; t < TSEQ; ++t) {
    const unsigned tg = (unsigned)(t + 1);
    const bool teach = ((t % period) < gtv);
    if (teach) {
      // stores of the register-prefetched X row (loaded last iteration)
#pragma unroll
      for (int e = 0; e < 4; ++e) {
        inp_f[xrow][xd0 + e] = xp[e];
        inp_bf[xrow][xd0 + e] = f2bf(xp[e]);
      }
    }
    __syncthreads();  // S1: inp ready; h_st holds h(t-1)

    ffrag4 ghr;
    float hp[4];  // w0 snapshots h_prev before gather overwrites h_st
    if (w < 3) {
      ffrag4 acc[4];
#pragma unroll
      for (int e = 0; e < 4; ++e) {
        acc[0][e] = bias_g; acc[1][e] = 0.f; acc[2][e] = 0.f; acc[3][e] = 0.f;
      }
#pragma unroll
      for (int ks = 0; ks < 32; ++ks) {
        const bfrag8 a = *(const bfrag8*)&h_st[c][ks * 32 + quad * 8];
        acc[ks & 3] = MFMA_B16(a, wB[ks], acc[ks & 3]);
      }
      ffrag4 gsum = acc[0] + acc[1] + acc[2] + acc[3];
      if (w == 1) {
#pragma unroll
        for (int i = 0; i < 4; ++i) gt_z[quad * 4 + i][c] = gsum[i];
      } else if (w == 2) {
#pragma unroll
        for (int i = 0; i < 4; ++i) gt_hn[quad * 4 + i][c] = gsum[i];
      } else {
        ghr = gsum;
#pragma unroll
        for (int i = 0; i < 4; ++i) hp[i] = bf2f(h_st[quad * 4 + i][j * 16 + c]);
      }
    } else {
      ffrag4 gir, giz, gin;
#pragma unroll
      for (int e = 0; e < 4; ++e) { gir[e] = 0.f; giz[e] = 0.f; gin[e] = bias_g; }
#pragma unroll
      for (int ks = 0; ks < 2; ++ks) {
        const bfrag8 a = *(const bfrag8*)&inp_bf[c][ks * 32 + quad * 8];
        gir = MFMA_B16(a, wB[0 + ks], gir);
        giz = MFMA_B16(a, wB[2 + ks], giz);
        gin = MFMA_B16(a, wB[4 + ks], gin);
      }
#pragma unroll
      for (int i = 0; i < 4; ++i) {
        gt_ir[quad * 4 + i][c] = gir[i];
        gt_iz[quad * 4 + i][c] = giz[i];
        gt_in[quad * 4 + i][c] = gin[i];
      }
    }
    __syncthreads();  // S2: gate tiles ready; h_st now dead until gather refill

    unsigned* hw = hb_g[t & 1];
    if (w == 0) {
      // gates -> h_new (bf16) -> htmp (wave-local repack) -> tagged publish
#pragma unroll
      for (int i = 0; i < 4; ++i) {
        const int row = quad * 4 + i;
        float r = 1.f / (1.f + __expf(-(ghr[i] + gt_ir[row][c])));
        float z = 1.f / (1.f + __expf(-(gt_z[row][c] + gt_iz[row][c])));
        float n = tanhf(gt_in[row][c] + r * gt_hn[row][c]);
        htmp[row][c] = f2bf((1.f - z) * n + z * hp[i]);
      }
      // TBAA-safe repack: same-typed (short) loads + compiler memory fence so
      // the reads can never be scheduled above the htmp stores.
      asm volatile("" ::: "memory");
      const int r = lane >> 2, q4 = (lane & 3) * 4;   // 4 cols = 4 dwords per lane
      unsigned d0 = ((unsigned)tg << 16) | (unsigned)(unsigned short)htmp[r][q4 + 0];
      unsigned d1 = ((unsigned)tg << 16) | (unsigned)(unsigned short)htmp[r][q4 + 1];
      unsigned d2 = ((unsigned)tg << 16) | (unsigned)(unsigned short)htmp[r][q4 + 2];
      unsigned d3 = ((unsigned)tg << 16) | (unsigned)(unsigned short)htmp[r][q4 + 3];
      ull w0v = ((ull)d1 << 32) | d0;
      ull w1v = ((ull)d3 << 32) | d2;
      ull* dst = (ull*)(hw + (size_t)r * 1024 + 16 * j + q4);
      __hip_atomic_store(dst, w0v, __ATOMIC_RELAXED, __HIP_MEMORY_SCOPE_SYSTEM);
      __hip_atomic_store(dst + 1, w1v, __ATOMIC_RELAXED, __HIP_MEMORY_SCOPE_SYSTEM);
      // open the gather gate AFTER the publish stores are issued (no drain).
      asm volatile("" ::: "memory");
      if (lane == 0) *(volatile int*)&pub_flag = (int)tg;
    } else {
      // perf-only gate: wait until w0 has issued its publish (LDS spin,
      // no fabric traffic). Correctness is still carried by the tags.
      while (*(volatile int*)&pub_flag < (int)tg) __builtin_amdgcn_s_sleep(1);
    }

    // issue next-teach-step X loads into registers: they fly during the
    // gather's retry window and are consumed at the next loop head.
    {
      const int tn = t + 1;
      if (tn < TSEQ && ((tn % period) < gtv)) {
        const float* xr = X + ((size_t)(g * MB + xrow) * TSEQ + tn) * INDIM;
#pragma unroll
        for (int e = 0; e < 4; ++e) xp[e] = (xd0 + e < INDIM) ? xr[xd0 + e] : 0.f;
      }
    }

    // gather h(t): the load IS the barrier — retry 16B chunks until all
    // tags == t+1. Each dword is (tag16|bf16): self-consistent at any width.
    {
      u32x4 v[16];
      const unsigned* gp = hw + (size_t)tid * 4;
#pragma unroll
      for (int s = 0; s < 16; ++s) GLOAD4(v[s], gp + s * 1024);
      asm volatile("s_waitcnt vmcnt(0)" ::: "memory");
      __builtin_amdgcn_sched_barrier(0);

      unsigned bad = 0;
#pragma unroll
      for (int s = 0; s < 16; ++s) {
        if ((v[s][0] >> 16) != tg || (v[s][1] >> 16) != tg ||
            (v[s][2] >> 16) != tg || (v[s][3] >> 16) != tg)
          bad |= (1u << s);
      }
      while (__ballot(bad != 0)) {
        // uniform per-chunk reload: lanes whose chunk is already good reload
        // harmlessly (tagged words are write-once per step per parity buffer)
#pragma unroll
        for (int s = 0; s < 16; ++s) {
          if (__ballot((bad >> s) & 1u)) GLOAD4(v[s], gp + s * 1024);
        }
        asm volatile("s_waitcnt vmcnt(0)" ::: "memory");
        __builtin_amdgcn_sched_barrier(0);
        bad = 0;
#pragma unroll
        for (int s = 0; s < 16; ++s) {
          if ((v[s][0] >> 16) != tg || (v[s][1] >> 16) != tg ||
              (v[s][2] >> 16) != tg || (v[s][3] >> 16) != tg)
            bad |= (1u << s);
        }
      }
#pragma unroll
      for (int s = 0; s < 16; ++s) {
        const int ci = tid + s * 256;          // chunk = 4 cols of one row
        const int row = ci >> 8;
        const int cb = (ci & 255) * 4;
        ull p = (ull)(v[s][0] & 0xFFFFu) | ((ull)(v[s][1] & 0xFFFFu) << 16) |
                ((ull)(v[s][2] & 0xFFFFu) << 32) | ((ull)(v[s][3] & 0xFFFFu) << 48);
        *(ull*)&h_st[row][cb] = p;
      }
    }
    __syncthreads();  // S3: h_st = h(t)

    // out(t) = inp(t) + h(t) @ Wp^T + bp
    // round-robin the OUT-writer so no single block is a systematic straggler
    const int wj = t & 63;
    const bool rep = (t + 1 < TSEQ) && !(((t + 1) % period) < gtv);
    if (rep || j == wj) {
      ffrag4 oa0, oa1;
#pragma unroll
      for (int e = 0; e < 4; ++e) { oa0[e] = bp_l; oa1[e] = 0.f; }
#pragma unroll
      for (int ks = 0; ks < 32; ++ks) {
        const bfrag8 a = *(const bfrag8*)&h_st[c][ks * 32 + quad * 8];
        if (ks & 1) oa1 = MFMA_B16(a, wp[ks], oa1);
        else        oa0 = MFMA_B16(a, wp[ks], oa0);
      }
      ffrag4 o = oa0 + oa1;
#pragma unroll
      for (int i = 0; i < 4; ++i) {
        const int row = quad * 4 + i;
        if (dd < INDIM) {
          float val = o[i] + inp_f[row][dd];
          if (j == wj) OUT[((size_t)(g * MB + row) * TSEQ + t) * INDIM + dd] = val;
          if (rep) { inp_f[row][dd] = val; inp_bf[row][dd] = f2bf(val); }
        } else if (rep) {
          inp_bf[row][dd] = 0;
        }
      }
    }
    // loop-head S1 orders inp writes vs next gi reads
  }
}

// ---------------- host ----------------

extern "C" void kernel_launch(void* const* d_in, const int* in_sizes, int n_in,
                              void* d_out, int out_size, void* d_ws, size_t ws_size,
                              hipStream_t stream) {
  const float* X    = (const float*)d_in[0];
  const float* W_ih = (const float*)d_in[1];
  const float* W_hh = (const float*)d_in[2];
  const float* b_ih = (const float*)d_in[3];
  const float* b_hh = (const float*)d_in[4];
  const float* W1   = (const float*)d_in[5];
  const float* b1   = (const float*)d_in[6];
  const float* W2   = (const float*)d_in[7];
  const float* b2   = (const float*)d_in[8];
  const float* W3   = (const float*)d_in[9];
  const float* b3   = (const float*)d_in[10];
  const int* pCL    = (const int*)d_in[11];
  const int* pGT    = (const int*)d_in[12];
  float* OUT = (float*)d_out;

  // layout: T2 aliases hb (dead before k_main; hb memset after)
  char* ws = (char*)d_ws;
  float* bp = (float*)(ws + 1024);        // 63 f32
  float* t1 = (float*)(ws + 2048);        // 1024 f32
  float* Wp = (float*)(ws + 8192);        // 63x1024 f32 (258048 B)
  float* T2 = (float*)(ws + 270336);      // 63x1024 f32 scratch (aliases hb)
  unsigned* hb = (unsigned*)(ws + 270336); // 2 x 4 x 16 x 1024 dwords = 512 KB
  if (ws_size < 795 * 1024) return;

  k_t1<<<256, 256, 0, stream>>>(W2, b1, b2, t1);
  k_gemm<<<dim3(64, 4), dim3(16, 16), 0, stream>>>(W3, W2, T2, INDIM, HIDDEN, HIDDEN);
  k_gemm<<<dim3(64, 4), dim3(16, 16), 0, stream>>>(T2, W1, Wp, INDIM, HIDDEN, HIDDEN);
  k_bp<<<1, 256, 0, stream>>>(W3, t1, b3, bp);
  hipMemsetAsync(hb, 0, (size_t)2 * NGRP * HB_DW * sizeof(unsigned), stream);  // tags := 0
  k_main<<<256, 256, 0, stream>>>(X, W_ih, W_hh, b_ih, b_hh, Wp, bp, pCL, pGT, hb, OUT);
}